// Round 13
// baseline (55.792 us; speedup 1.0000x reference)
//
#include <hip/hip_runtime.h>
#include <math.h>

#define BATCH 8
#define TLEN  512
#define DDIM  512
#define TOUT  608   // 512 + 96
#define KSEL  32
#define DT    8     // d columns per block in k1

#define TWO_PI_OVER_512 0.0122718463030851562f
#define SC (2.0f / 512.0f)

typedef __attribute__((ext_vector_type(8))) short short8;
typedef __attribute__((ext_vector_type(4))) float f32x4;

// ws layout (bytes):
//   BmT: [8][512 d][512 k2] ushort(bf16)  at 0        (4,194,304 B)
//   Wk : [512 t][512 k2]   ushort(bf16)  at 4194304  (524,288 B)
#define BMT_OFF 0
#define WK_OFF  4194304

__device__ __forceinline__ unsigned short f2bf(float f) {
    unsigned u = __float_as_uint(f);
    return (unsigned short)((u + 0x7FFF + ((u >> 16) & 1)) >> 16);   // RNE
}

// 16-point DFT twiddles (exact constants), e^{-2pi i n/16} = CC[n] - i*SS[n]
__device__ __constant__ const float CC16[16] = {
     1.f,  0.92387953251128674f,  0.70710678118654752f,  0.38268343236508977f,
     0.f, -0.38268343236508977f, -0.70710678118654752f, -0.92387953251128674f,
    -1.f, -0.92387953251128674f, -0.70710678118654752f, -0.38268343236508977f,
     0.f,  0.38268343236508977f,  0.70710678118654752f,  0.92387953251128674f };
__device__ __constant__ const float SS16[16] = {
     0.f,  0.38268343236508977f,  0.70710678118654752f,  0.92387953251128674f,
     1.f,  0.92387953251128674f,  0.70710678118654752f,  0.38268343236508977f,
     0.f, -0.38268343236508977f, -0.70710678118654752f, -0.92387953251128674f,
    -1.f, -0.92387953251128674f, -0.70710678118654752f, -0.38268343236508977f };

// ---------------------------------------------------------------------------
// Kernel 1: FFT (radix 16x32) + top-32 + emit masked bf16 spectrum BmT[d][k2].
// XCD swizzle: dtile = 8*(bid&7) + ((bid>>3)&7) -> each XCD owns 8 contiguous
// d-tiles. Also emits one Wk t-row per block (t = bid).
// ---------------------------------------------------------------------------
__global__ __launch_bounds__(512, 4) void fft_topk_kernel(const float* __restrict__ x,
                                                          unsigned short* __restrict__ BmT,
                                                          unsigned short* __restrict__ Wk) {
    __shared__ float2 Xl[DT][257];                 // 16,448 B
    __shared__ float  ysr[16 * 33 * 9];            // 19,008 B
    __shared__ float  ysi[16 * 33 * 9];            // 19,008 B
    __shared__ float2 tw[512];                     // 4,096 B

    const int tid = threadIdx.x;
    const int bid = blockIdx.x;
    const int b   = bid >> 6;
    const int d0  = ((bid & 7) * 8 + ((bid >> 3) & 7)) * DT;   // XCD-contiguous d

    {   // twiddle table: tw[n] = (cos, sin)(2 pi n / 512)
        float s, c;
        sincosf((float)tid * TWO_PI_OVER_512, &s, &c);
        tw[tid] = make_float2(c, s);
    }

    // ---- stage A: thread = (aA, dA, h) computes q rows [8h, 8h+8) ----
    {
        const int h   = tid >> 8;
        const int rem = tid & 255;
        const int aA  = rem >> 3;        // 0..31
        const int dA  = rem & 7;
        const float* xb = x + ((size_t)b * TLEN + aA) * DDIM + d0 + dA;
        float xv[16];
        #pragma unroll
        for (int c = 0; c < 16; ++c)
            xv[c] = xb[(size_t)c * 32 * DDIM];

        #pragma unroll
        for (int qn = 0; qn < 8; ++qn) {
            const int q = qn + 8 * h;
            float sr = 0.f, si = 0.f;
            #pragma unroll
            for (int c = 0; c < 16; ++c) {
                const int n = (c * q) & 15;
                sr = fmaf(xv[c],  CC16[n], sr);
                si = fmaf(xv[c], -SS16[n], si);
            }
            ysr[(q * 33 + aA) * 9 + dA] = sr;
            ysi[(q * 33 + aA) * 9 + dA] = si;
        }
    }
    __syncthreads();   // ys + tw ready

    // ---- stage B: thread = (ahalf, dB, kk) ----
    {
        const int ahalf = tid & 1;
        const int dB    = (tid >> 1) & 7;
        const int kk    = tid >> 4;      // 0..31
        const int qq    = kk & 15;

        float Pr, Pi;
        if (ahalf == 0) { Pr = 1.f; Pi = 0.f; }
        else {
            float2 w = tw[(16 * kk) & 511];
            Pr = w.x; Pi = -w.y;
        }
        const float2 w2 = tw[kk];        // e^{-2pi i kk/512} = (w2.x, -w2.y)
        const float stc = w2.x, sts = w2.y;

        float ar[8] = {}, ai[8] = {};
        #pragma unroll
        for (int aa = 0; aa < 16; ++aa) {
            const int arow = ahalf * 16 + aa;     // (arow*u)&15 == (aa*u)&15
            float Yr = ysr[(qq * 33 + arow) * 9 + dB];
            float Yi = ysi[(qq * 33 + arow) * 9 + dB];
            float zr = Yr * Pr - Yi * Pi;
            float zi = Yr * Pi + Yi * Pr;
            #pragma unroll
            for (int u = 0; u < 8; ++u) {
                const int n = (aa * u) & 15;
                ar[u] = fmaf(zr, CC16[n], fmaf(zi,  SS16[n], ar[u]));
                ai[u] = fmaf(zi, CC16[n], fmaf(-zr, SS16[n], ai[u]));
            }
            float npr = fmaf(Pr, stc,  Pi * sts);
            Pi        = fmaf(Pi, stc, -Pr * sts);
            Pr        = npr;
        }

        #pragma unroll
        for (int u = 0; u < 8; ++u) {
            ar[u] += __shfl_xor(ar[u], 1);
            ai[u] += __shfl_xor(ai[u], 1);
        }
        #pragma unroll
        for (int v = 0; v < 4; ++v) {
            const int u = ahalf * 4 + v;
            Xl[dB][kk + 32 * u] = make_float2(ar[u], ai[u]);
        }
    }
    __syncthreads();   // Xl complete

    // ---- Wk row emission: t = bid, m = tid (waves 0..3 only) ----
    if (tid < 256) {
        float2 w = tw[(bid * tid) & 511];
        unsigned val = (unsigned)f2bf(w.x * SC) | ((unsigned)f2bf(-w.y * SC) << 16);
        *(unsigned*)&Wk[((size_t)bid << 9) + 2 * tid] = val;
    }

    // ---- topk: wave w handles column w; emit masked bf16 rows ----
    {
        const int l  = tid & 63;
        const int dd = tid >> 6;         // 0..7
        const unsigned long long below = ((unsigned long long)1 << l) - 1;

        float zr[4], zi[4];
        unsigned vb[4];
        int mm[4];
        #pragma unroll
        for (int s = 0; s < 4; ++s) {
            int m = 1 + l + 64 * s;
            mm[s] = m;
            if (m <= 255) {
                float2 z = Xl[dd][m];
                zr[s] = z.x; zi[s] = z.y;
                vb[s] = __float_as_uint(fmaf(z.x, z.x, z.y * z.y));
            } else { zr[s] = 0.f; zi[s] = 0.f; vb[s] = 0u; }
        }

        unsigned tau = 0;
        for (int bit = 30; bit >= 0; --bit) {
            unsigned cand = tau | (1u << bit);
            int cnt = __popcll(__ballot(vb[0] >= cand))
                    + __popcll(__ballot(vb[1] >= cand))
                    + __popcll(__ballot(vb[2] >= cand))
                    + __popcll(__ballot(vb[3] >= cand));
            if (cnt >= KSEL) tau = cand;
        }

        unsigned long long beq[4];
        int cgt = 0;
        #pragma unroll
        for (int s = 0; s < 4; ++s) {
            beq[s] = __ballot(vb[s] == tau);
            cgt += __popcll(__ballot(vb[s] > tau));
        }
        const int need = KSEL - cgt;     // ties taken at == tau

        unsigned short* Brow = BmT + ((size_t)(b * DDIM + d0 + dd) << 9);
        int be = 0;
        #pragma unroll
        for (int s = 0; s < 4; ++s) {
            bool keep = (vb[s] > tau);
            if (vb[s] == tau) {
                int r = be + __popcll(beq[s] & below);
                keep = (r < need);
            }
            be += __popcll(beq[s]);
            unsigned val = keep ? ((unsigned)f2bf(zr[s]) | ((unsigned)f2bf(zi[s]) << 16)) : 0u;
            int mi = mm[s] & 255;        // m=256 lane remaps to k2 rows 0..1 (zeros)
            *(unsigned*)(Brow + 2 * mi) = val;
        }
    }
}

// ---------------------------------------------------------------------------
// Kernel 2: out[b] = Wk @ BmT[b]^T via MFMA 16x16x32 bf16.
// XCD swizzle: bd = bid&7 -> producers/consumers of a BmT slice share an XCD.
// ---------------------------------------------------------------------------
__global__ __launch_bounds__(512, 4) void gemm_kernel(const unsigned short* __restrict__ Wk,
                                                      const unsigned short* __restrict__ BmT,
                                                      float* __restrict__ out) {
    __shared__ unsigned short Al[64][72];   // pad 72 vs bank conflicts
    __shared__ unsigned short Bl[64][72];

    const int tid = threadIdx.x;
    const int bid = blockIdx.x;
    const int bt  = bid >> 6;            // Wk t-tile
    const int b   = (bid >> 3) & 7;
    const int bd  = bid & 7;             // = bid%8 -> XCD id shares BmT slice

    const int wid  = tid >> 6;           // 0..7
    const int l    = tid & 63;
    const int wm   = wid & 3;            // t-slice of 16
    const int wn   = wid >> 2;           // d-slice of 32
    const int lrow = l & 15;
    const int lk8  = (l >> 4) * 8;

    const int srow = tid >> 3;           // 0..63 staging row
    const int soff = (tid & 7) * 8;      // ushort offset (16 B)

    const unsigned short* Wrow = Wk  + (size_t)(bt * 64 + srow) * 512 + soff;
    const unsigned short* Brow = BmT + ((size_t)(b * DDIM + bd * 64 + srow)) * 512 + soff;

    f32x4 acc0 = {0.f, 0.f, 0.f, 0.f};
    f32x4 acc1 = {0.f, 0.f, 0.f, 0.f};

    for (int kc = 0; kc < 512; kc += 64) {
        uint4 av = *(const uint4*)(Wrow + kc);
        uint4 bv = *(const uint4*)(Brow + kc);
        __syncthreads();                 // previous chunk's reads complete
        *(uint4*)&Al[srow][soff] = av;
        *(uint4*)&Bl[srow][soff] = bv;
        __syncthreads();

        #pragma unroll
        for (int ks = 0; ks < 2; ++ks) {
            short8 af  = *(const short8*)&Al[wm * 16 + lrow][ks * 32 + lk8];
            short8 bf0 = *(const short8*)&Bl[wn * 32 + lrow][ks * 32 + lk8];
            short8 bf1 = *(const short8*)&Bl[wn * 32 + 16 + lrow][ks * 32 + lk8];
            acc0 = __builtin_amdgcn_mfma_f32_16x16x32_bf16(af, bf0, acc0, 0, 0, 0);
            acc1 = __builtin_amdgcn_mfma_f32_16x16x32_bf16(af, bf1, acc1, 0, 0, 0);
        }
    }

    const int tg = bt * 64 + wm * 16 + (l >> 4) * 4;
    const int dg = bd * 64 + wn * 32 + (l & 15);
    float* ob = out + (size_t)b * TOUT * DDIM;
    #pragma unroll
    for (int r = 0; r < 4; ++r) {
        const int t = tg + r;
        ob[(size_t)t * DDIM + dg]      = acc0[r];
        ob[(size_t)t * DDIM + dg + 16] = acc1[r];
        if (t < 96) {
            ob[(size_t)(t + 512) * DDIM + dg]      = acc0[r];
            ob[(size_t)(t + 512) * DDIM + dg + 16] = acc1[r];
        }
    }
}

extern "C" void kernel_launch(void* const* d_in, const int* in_sizes, int n_in,
                              void* d_out, int out_size, void* d_ws, size_t ws_size,
                              hipStream_t stream) {
    const float* x   = (const float*)d_in[0];
    float*       out = (float*)d_out;
    unsigned short* BmT = (unsigned short*)((char*)d_ws + BMT_OFF);
    unsigned short* Wk  = (unsigned short*)((char*)d_ws + WK_OFF);

    // ATTRIBUTION EXPERIMENT: k1 launched 3x (idempotent, byte-identical
    // writes) so its per-dispatch time surfaces in rocprof and the total's
    // delta vs R10 gives 2x k1. Revert to single launch next round.
    fft_topk_kernel<<<BATCH * 64, 512, 0, stream>>>(x, BmT, Wk);
    fft_topk_kernel<<<BATCH * 64, 512, 0, stream>>>(x, BmT, Wk);
    fft_topk_kernel<<<BATCH * 64, 512, 0, stream>>>(x, BmT, Wk);
    gemm_kernel<<<BATCH * 64, 512, 0, stream>>>(Wk, BmT, out);
}

// Round 14
// 26.635 us; speedup vs baseline: 2.0947x; 2.0947x over previous
//
#include <hip/hip_runtime.h>
#include <math.h>

#define BATCH 8
#define TLEN  512
#define DDIM  512
#define TOUT  608   // 512 + 96
#define KSEL  32
#define DT    8     // d columns per block in k1

#define TWO_PI_OVER_512 0.0122718463030851562f
#define SC (2.0f / 512.0f)

typedef __attribute__((ext_vector_type(8))) short short8;
typedef __attribute__((ext_vector_type(4))) float f32x4;

// ws layout (bytes):
//   BmT: [8][512 d][512 k2] ushort(bf16)  at 0        (4,194,304 B)
//   Wk : [512 t][512 k2]   ushort(bf16)  at 4194304  (524,288 B)
#define BMT_OFF 0
#define WK_OFF  4194304

__device__ __forceinline__ unsigned short f2bf(float f) {
    unsigned u = __float_as_uint(f);
    return (unsigned short)((u + 0x7FFF + ((u >> 16) & 1)) >> 16);   // RNE
}

// 16-point DFT twiddles (exact constants), e^{-2pi i n/16} = CC[n] - i*SS[n]
__device__ __constant__ const float CC16[16] = {
     1.f,  0.92387953251128674f,  0.70710678118654752f,  0.38268343236508977f,
     0.f, -0.38268343236508977f, -0.70710678118654752f, -0.92387953251128674f,
    -1.f, -0.92387953251128674f, -0.70710678118654752f, -0.38268343236508977f,
     0.f,  0.38268343236508977f,  0.70710678118654752f,  0.92387953251128674f };
__device__ __constant__ const float SS16[16] = {
     0.f,  0.38268343236508977f,  0.70710678118654752f,  0.92387953251128674f,
     1.f,  0.92387953251128674f,  0.70710678118654752f,  0.38268343236508977f,
     0.f, -0.38268343236508977f, -0.70710678118654752f, -0.92387953251128674f,
    -1.f, -0.92387953251128674f, -0.70710678118654752f, -0.38268343236508977f };

// ---------------------------------------------------------------------------
// Kernel 1: FFT (radix 16x32) + top-32 + emit masked bf16 spectrum BmT[d][k2].
// Stage B now PRELOADS its 16 Y-complex values and 16 exact phasors into
// registers (one batched lgkmcnt wait instead of 32 just-in-time stalls;
// serial phasor-rotation chain eliminated).
// XCD swizzle: dtile = 8*(bid&7) + ((bid>>3)&7). Emits one Wk row (t = bid).
// ---------------------------------------------------------------------------
__global__ __launch_bounds__(512, 4) void fft_topk_kernel(const float* __restrict__ x,
                                                          unsigned short* __restrict__ BmT,
                                                          unsigned short* __restrict__ Wk) {
    __shared__ float2 Xl[DT][257];                 // 16,448 B
    __shared__ float  ysr[16 * 33 * 9];            // 19,008 B
    __shared__ float  ysi[16 * 33 * 9];            // 19,008 B
    __shared__ float2 tw[512];                     // 4,096 B

    const int tid = threadIdx.x;
    const int bid = blockIdx.x;
    const int b   = bid >> 6;
    const int d0  = ((bid & 7) * 8 + ((bid >> 3) & 7)) * DT;   // XCD-contiguous d

    {   // twiddle table: tw[n] = (cos, sin)(2 pi n / 512)
        float s, c;
        sincosf((float)tid * TWO_PI_OVER_512, &s, &c);
        tw[tid] = make_float2(c, s);
    }

    // ---- stage A: thread = (aA, dA, h) computes q rows [8h, 8h+8) ----
    {
        const int h   = tid >> 8;
        const int rem = tid & 255;
        const int aA  = rem >> 3;        // 0..31
        const int dA  = rem & 7;
        const float* xb = x + ((size_t)b * TLEN + aA) * DDIM + d0 + dA;
        float xv[16];
        #pragma unroll
        for (int c = 0; c < 16; ++c)
            xv[c] = xb[(size_t)c * 32 * DDIM];

        #pragma unroll
        for (int qn = 0; qn < 8; ++qn) {
            const int q = qn + 8 * h;
            float sr = 0.f, si = 0.f;
            #pragma unroll
            for (int c = 0; c < 16; ++c) {
                const int n = (c * q) & 15;
                sr = fmaf(xv[c],  CC16[n], sr);
                si = fmaf(xv[c], -SS16[n], si);
            }
            ysr[(q * 33 + aA) * 9 + dA] = sr;
            ysi[(q * 33 + aA) * 9 + dA] = si;
        }
    }
    __syncthreads();   // ys + tw ready

    // ---- stage B: thread = (ahalf, dB, kk); register-preloaded ----
    {
        const int ahalf = tid & 1;
        const int dB    = (tid >> 1) & 7;
        const int kk    = tid >> 4;      // 0..31
        const int qq    = kk & 15;

        const int ybase = (qq * 33 + ahalf * 16) * 9 + dB;
        float Yr_[16], Yi_[16], Pr_[16], Pi_[16];
        #pragma unroll
        for (int aa = 0; aa < 16; ++aa) {
            Yr_[aa] = ysr[ybase + aa * 9];
            Yi_[aa] = ysi[ybase + aa * 9];
        }
        #pragma unroll
        for (int aa = 0; aa < 16; ++aa) {
            const int arow = ahalf * 16 + aa;
            float2 w = tw[(arow * kk) & 511];    // exact e^{-2pi i arow kk/512}
            Pr_[aa] = w.x;
            Pi_[aa] = -w.y;
        }

        float ar[8] = {}, ai[8] = {};
        #pragma unroll
        for (int aa = 0; aa < 16; ++aa) {
            float zr = Yr_[aa] * Pr_[aa] - Yi_[aa] * Pi_[aa];
            float zi = Yr_[aa] * Pi_[aa] + Yi_[aa] * Pr_[aa];
            #pragma unroll
            for (int u = 0; u < 8; ++u) {
                const int n = (aa * u) & 15;
                ar[u] = fmaf(zr, CC16[n], fmaf(zi,  SS16[n], ar[u]));
                ai[u] = fmaf(zi, CC16[n], fmaf(-zr, SS16[n], ai[u]));
            }
        }

        #pragma unroll
        for (int u = 0; u < 8; ++u) {
            ar[u] += __shfl_xor(ar[u], 1);
            ai[u] += __shfl_xor(ai[u], 1);
        }
        #pragma unroll
        for (int v = 0; v < 4; ++v) {
            const int u = ahalf * 4 + v;
            Xl[dB][kk + 32 * u] = make_float2(ar[u], ai[u]);
        }
    }
    __syncthreads();   // Xl complete

    // ---- Wk row emission: t = bid, m = tid (waves 0..3 only) ----
    if (tid < 256) {
        float2 w = tw[(bid * tid) & 511];
        unsigned val = (unsigned)f2bf(w.x * SC) | ((unsigned)f2bf(-w.y * SC) << 16);
        *(unsigned*)&Wk[((size_t)bid << 9) + 2 * tid] = val;
    }

    // ---- topk: wave w handles column w; emit masked bf16 rows ----
    {
        const int l  = tid & 63;
        const int dd = tid >> 6;         // 0..7
        const unsigned long long below = ((unsigned long long)1 << l) - 1;

        float zr[4], zi[4];
        unsigned vb[4];
        int mm[4];
        #pragma unroll
        for (int s = 0; s < 4; ++s) {
            int m = 1 + l + 64 * s;
            mm[s] = m;
            if (m <= 255) {
                float2 z = Xl[dd][m];
                zr[s] = z.x; zi[s] = z.y;
                vb[s] = __float_as_uint(fmaf(z.x, z.x, z.y * z.y));
            } else { zr[s] = 0.f; zi[s] = 0.f; vb[s] = 0u; }
        }

        unsigned tau = 0;
        for (int bit = 30; bit >= 0; --bit) {
            unsigned cand = tau | (1u << bit);
            int cnt = __popcll(__ballot(vb[0] >= cand))
                    + __popcll(__ballot(vb[1] >= cand))
                    + __popcll(__ballot(vb[2] >= cand))
                    + __popcll(__ballot(vb[3] >= cand));
            if (cnt >= KSEL) tau = cand;
        }

        unsigned long long beq[4];
        int cgt = 0;
        #pragma unroll
        for (int s = 0; s < 4; ++s) {
            beq[s] = __ballot(vb[s] == tau);
            cgt += __popcll(__ballot(vb[s] > tau));
        }
        const int need = KSEL - cgt;     // ties taken at == tau

        unsigned short* Brow = BmT + ((size_t)(b * DDIM + d0 + dd) << 9);
        int be = 0;
        #pragma unroll
        for (int s = 0; s < 4; ++s) {
            bool keep = (vb[s] > tau);
            if (vb[s] == tau) {
                int r = be + __popcll(beq[s] & below);
                keep = (r < need);
            }
            be += __popcll(beq[s]);
            unsigned val = keep ? ((unsigned)f2bf(zr[s]) | ((unsigned)f2bf(zi[s]) << 16)) : 0u;
            int mi = mm[s] & 255;        // m=256 lane remaps to k2 rows 0..1 (zeros)
            *(unsigned*)(Brow + 2 * mi) = val;
        }
    }
}

// ---------------------------------------------------------------------------
// Kernel 2: out[b] = Wk @ BmT[b]^T via MFMA 16x16x32 bf16.
// K-chunk 128 (4 iterations, half the barriers) + next-chunk global prefetch
// overlapped with the MFMA cluster. XCD swizzle: bd = bid&7.
// ---------------------------------------------------------------------------
__global__ __launch_bounds__(512, 4) void gemm_kernel(const unsigned short* __restrict__ Wk,
                                                      const unsigned short* __restrict__ BmT,
                                                      float* __restrict__ out) {
    __shared__ unsigned short Al[64][136];   // pad 136 (stride ≡ 4 dwords mod 32)
    __shared__ unsigned short Bl[64][136];

    const int tid = threadIdx.x;
    const int bid = blockIdx.x;
    const int bt  = bid >> 6;            // Wk t-tile
    const int b   = (bid >> 3) & 7;
    const int bd  = bid & 7;             // = bid%8 -> XCD id shares BmT slice

    const int wid  = tid >> 6;           // 0..7
    const int l    = tid & 63;
    const int wm   = wid & 3;            // t-slice of 16
    const int wn   = wid >> 2;           // d-slice of 32
    const int lrow = l & 15;
    const int lk8  = (l >> 4) * 8;

    const int srow = tid >> 3;           // 0..63 staging row
    const int soff = (tid & 7) * 8;      // ushort offset (16 B)

    const unsigned short* Wrow = Wk  + (size_t)(bt * 64 + srow) * 512 + soff;
    const unsigned short* Brow = BmT + ((size_t)(b * DDIM + bd * 64 + srow)) * 512 + soff;

    f32x4 acc0 = {0.f, 0.f, 0.f, 0.f};
    f32x4 acc1 = {0.f, 0.f, 0.f, 0.f};

    uint4 av0 = *(const uint4*)(Wrow);
    uint4 av1 = *(const uint4*)(Wrow + 64);
    uint4 bv0 = *(const uint4*)(Brow);
    uint4 bv1 = *(const uint4*)(Brow + 64);

    for (int kc = 0; kc < 512; kc += 128) {
        __syncthreads();                 // previous chunk's LDS reads complete
        *(uint4*)&Al[srow][soff]      = av0;
        *(uint4*)&Al[srow][soff + 64] = av1;
        *(uint4*)&Bl[srow][soff]      = bv0;
        *(uint4*)&Bl[srow][soff + 64] = bv1;
        __syncthreads();

        if (kc + 128 < 512) {            // prefetch overlaps MFMA cluster
            av0 = *(const uint4*)(Wrow + kc + 128);
            av1 = *(const uint4*)(Wrow + kc + 192);
            bv0 = *(const uint4*)(Brow + kc + 128);
            bv1 = *(const uint4*)(Brow + kc + 192);
        }

        #pragma unroll
        for (int ks = 0; ks < 4; ++ks) {
            short8 af  = *(const short8*)&Al[wm * 16 + lrow][ks * 32 + lk8];
            short8 bf0 = *(const short8*)&Bl[wn * 32 + lrow][ks * 32 + lk8];
            short8 bf1 = *(const short8*)&Bl[wn * 32 + 16 + lrow][ks * 32 + lk8];
            acc0 = __builtin_amdgcn_mfma_f32_16x16x32_bf16(af, bf0, acc0, 0, 0, 0);
            acc1 = __builtin_amdgcn_mfma_f32_16x16x32_bf16(af, bf1, acc1, 0, 0, 0);
        }
    }

    const int tg = bt * 64 + wm * 16 + (l >> 4) * 4;
    const int dg = bd * 64 + wn * 32 + (l & 15);
    float* ob = out + (size_t)b * TOUT * DDIM;
    #pragma unroll
    for (int r = 0; r < 4; ++r) {
        const int t = tg + r;
        ob[(size_t)t * DDIM + dg]      = acc0[r];
        ob[(size_t)t * DDIM + dg + 16] = acc1[r];
        if (t < 96) {
            ob[(size_t)(t + 512) * DDIM + dg]      = acc0[r];
            ob[(size_t)(t + 512) * DDIM + dg + 16] = acc1[r];
        }
    }
}

extern "C" void kernel_launch(void* const* d_in, const int* in_sizes, int n_in,
                              void* d_out, int out_size, void* d_ws, size_t ws_size,
                              hipStream_t stream) {
    const float* x   = (const float*)d_in[0];
    float*       out = (float*)d_out;
    unsigned short* BmT = (unsigned short*)((char*)d_ws + BMT_OFF);
    unsigned short* Wk  = (unsigned short*)((char*)d_ws + WK_OFF);

    fft_topk_kernel<<<BATCH * 64, 512, 0, stream>>>(x, BmT, Wk);
    gemm_kernel<<<BATCH * 64, 512, 0, stream>>>(Wk, BmT, out);
}